// Round 13
// baseline (75.975 us; speedup 1.0000x reference)
//
#include <hip/hip_runtime.h>

// ---------------------------------------------------------------------------
// HR2HK: H[k, N*13, N*13] from edge/node features, Hermitian fold-in.
// (Round-9 structure — best verified at 54.3 µs — plus non-temporal output
// stores: output is write-once/never-read, so bypass L2 temporal allocation.)
// Launch sequence:
//  hipMemsetAsync(cnt) : clear per-node counters
//  bucket_fill         : per-node incident-entry buckets via global atomics
//                        (packed (other<<18)|(e<<1)|flag). No CSR, no scan.
//  hr2hk_main (DIM x kgroups blocks): block (a=n1*13+r, kg) stages incident
//    entries ONCE (hop 13-segments, per-(entry,k) phases with ecs read
//    straight from L2, chain index by other-node; 2 barriers), then a
//    BARRIER-FREE stream loop: each thread walks the chain ONCE per
//    column-quad, accumulates ALL KB k-slices in registers (static
//    indexing), and issues KB coalesced nontemporal float4 stores. Every
//    output byte written exactly once; no global atomics.
// Dual layout keyed off out_size (proven round 3):
//   out_size >= 2*K*DIM^2 : interleaved complex64 ; else real-part-only f32.
// Node-degree overflow -> correct in-block global-atomic path (never taken).
// Guard failure -> verified round-3 3-kernel fallback.
// ---------------------------------------------------------------------------

typedef float f32x4 __attribute__((ext_vector_type(4)));   // native vector for
                                                           // nontemporal builtin

// orbital structure: l = [0,0,1,1,2], sizes {1,1,3,3,5}, offsets {0,1,2,5,8}
__device__ __forceinline__ void orb_of(int r, int& i, int& ri, int& nv) {
    if (r < 1)      { i = 0; ri = r;     nv = 1; }
    else if (r < 2) { i = 1; ri = r - 1; nv = 1; }
    else if (r < 5) { i = 2; ri = r - 2; nv = 3; }
    else if (r < 8) { i = 3; ri = r - 5; nv = 3; }
    else            { i = 4; ri = r - 8; nv = 5; }
}
__device__ __forceinline__ int offs_of(int i) {
    return i == 0 ? 0 : (i == 1 ? 1 : (i == 2 ? 2 : (i == 3 ? 5 : 8)));
}
__device__ __forceinline__ int rowstart_of(int i) {   // {0,13,25,58,82}
    return i == 0 ? 0 : (i == 1 ? 13 : (i == 2 ? 25 : (i == 3 ? 58 : 82)));
}
__device__ __forceinline__ int pmap(int r, int c) {
    int i, ri, nvi, j, cj, nvj;
    orb_of(r, i, ri, nvi);
    orb_of(c, j, cj, nvj);
    return 13 * offs_of(i) + nvi * offs_of(j) + ri * nvj + cj;
}
__device__ __forceinline__ int nmap(int r, int c) {
    int i, ri, nvi, j, cj, nvj;
    orb_of(r, i, ri, nvi);
    orb_of(c, j, cj, nvj);
    if (i <= j)
        return rowstart_of(i) + nvi * (offs_of(j) - offs_of(i)) + ri * nvj + cj;
    else
        return rowstart_of(j) + nvj * (offs_of(i) - offs_of(j)) + cj * nvi + ri;
}

constexpr float TWO_PI = 6.28318530717958647692f;
constexpr int CAPC = 128;   // per-node incident-entry capacity

// ========================= prep: per-node buckets ==========================
__global__ __launch_bounds__(256) void bucket_fill(const int* __restrict__ eidx,
                                                   int* __restrict__ cnt,
                                                   int* __restrict__ bkt,
                                                   int E) {
    int e = blockIdx.x * 256 + threadIdx.x;
    if (e >= E) return;
    int s = eidx[e], d = eidx[E + e];
    int p = atomicAdd(&cnt[s], 1);
    if (p < CAPC) bkt[s * CAPC + p] = (d << 18) | (e << 1);
    int q = atomicAdd(&cnt[d], 1);
    if (q < CAPC) bkt[d * CAPC + q] = (s << 18) | (e << 1) | 1;
}

// ============================ main row kernel ==============================
// block = (kg, a): computes rows a of k-slices [kg*KB, kg*KB+kb) with the
// chain walked ONCE per column, k accumulated in registers.
template <int CPLX, int KB>
__global__ __launch_bounds__(256) void hr2hk_main(const float* __restrict__ ef,
                                                  const float* __restrict__ nf,
                                                  const float* __restrict__ kp,
                                                  const float* __restrict__ ecs,
                                                  const int*   __restrict__ eidx,
                                                  const int*   __restrict__ cnt,
                                                  const int*   __restrict__ bkt,
                                                  float* __restrict__ out,
                                                  int N, int E, int K) {
    const int DIM  = N * 13;
    const int rowf = CPLX ? DIM * 2 : DIM;   // floats per row (mult of 4, guarded)
    const int row4 = rowf >> 2;
    const int a   = blockIdx.x % DIM;
    const int kg  = blockIdx.x / DIM;
    const int n1  = a / 13, r = a - n1 * 13;
    const int k0  = kg * KB;
    const int kb  = (K - k0 < KB) ? (K - k0) : KB;
    const int tid = threadIdx.x;

    __shared__ float h_sh[CAPC * 13];
    __shared__ float ph_sh[CAPC * KB * (CPLX ? 2 : 1)];
    __shared__ int   lst[CAPC];
    __shared__ int   head[256];
    __shared__ int   nxt[CAPC];
    __shared__ float dseg[13];
    __shared__ int   pm_s[13], pm_d[13];
    __shared__ float kp_sh[KB * 3];

    const int cnt_n = cnt[n1];
    const int cb = (cnt_n > CAPC) ? 0 : cnt_n;   // overflow -> gather path off

    head[tid] = -1;
    if (tid < 13) {
        pm_s[tid] = pmap(r, tid);
        pm_d[tid] = pmap(tid, r);
        dseg[tid] = 0.5f * (nf[n1 * 107 + nmap(r, tid)] + nf[n1 * 107 + nmap(tid, r)]);
    }
    if (tid < kb * 3) kp_sh[tid] = kp[k0 * 3 + tid];
    if (tid < cb) lst[tid] = bkt[n1 * CAPC + tid];
    __syncthreads();

    // chain build + phases (ecs straight from L2) + hop staging, one barrier
    if (tid < cb) {
        int o = (int)((unsigned)lst[tid] >> 18);
        nxt[tid] = atomicExch(&head[o], tid);
    }
    for (int t = tid; t < cb * KB; t += 256) {
        int li = t / KB, kk = t - li * KB;
        if (kk < kb) {
            int entry = lst[li];
            int e = (int)(((unsigned)entry >> 1) & 0x1FFFF);
            float sx = ecs[e * 3], sy = ecs[e * 3 + 1], sz = ecs[e * 3 + 2];
            float dot = kp_sh[kk * 3]     * sx
                      + kp_sh[kk * 3 + 1] * sy
                      + kp_sh[kk * 3 + 2] * sz;
            float th = TWO_PI * dot;
            if (CPLX) {
                float sn, co;
                sincosf(th, &sn, &co);
                ph_sh[(li * KB + kk) * 2]     = co;
                ph_sh[(li * KB + kk) * 2 + 1] = (entry & 1) ? sn : -sn;  // pre-folded
            } else {
                ph_sh[li * KB + kk] = cosf(th);
            }
        }
    }
    for (int t = tid; t < cb * 13; t += 256) {
        int li = t / 13, c = t - li * 13;
        int entry = lst[li];
        int e = (int)(((unsigned)entry >> 1) & 0x1FFFF);
        h_sh[li * 13 + c] = ef[(long)e * 169 + ((entry & 1) ? pm_d[c] : pm_s[c])];
    }
    __syncthreads();

    // ---- barrier-free streaming: chain walked once per col, k in registers --
    for (int t = tid; t < row4; t += 256) {
        float acc[KB][4];                       // static indexing (unrolled)
        if (CPLX) {
#pragma unroll
            for (int j = 0; j < 2; ++j) {       // two complex cols per float4
                int col = 2 * t + j;
                int o = (int)((unsigned)col / 13u);
                int cc = col - o * 13;
                float dre = (o == n1) ? dseg[cc] : 0.f;
#pragma unroll
                for (int kk = 0; kk < KB; ++kk) {
                    acc[kk][2 * j]     = dre;
                    acc[kk][2 * j + 1] = 0.f;
                }
                for (int li = head[o]; li >= 0; li = nxt[li]) {
                    float h = h_sh[li * 13 + cc];
#pragma unroll
                    for (int kk = 0; kk < KB; ++kk) {
                        acc[kk][2 * j]     += h * ph_sh[(li * KB + kk) * 2];
                        acc[kk][2 * j + 1] += h * ph_sh[(li * KB + kk) * 2 + 1];
                    }
                }
            }
        } else {
#pragma unroll
            for (int j = 0; j < 4; ++j) {
                int col = 4 * t + j;
                int o = (int)((unsigned)col / 13u);
                int cc = col - o * 13;
                float d = (o == n1) ? dseg[cc] : 0.f;
#pragma unroll
                for (int kk = 0; kk < KB; ++kk) acc[kk][j] = d;
                for (int li = head[o]; li >= 0; li = nxt[li]) {
                    float h = h_sh[li * 13 + cc];
#pragma unroll
                    for (int kk = 0; kk < KB; ++kk)
                        acc[kk][j] += h * ph_sh[li * KB + kk];
                }
            }
        }
#pragma unroll
        for (int kk = 0; kk < KB; ++kk) {
            if (kk < kb) {
                long base = ((long)(k0 + kk) * DIM + a) * (long)rowf;
                f32x4 v = {acc[kk][0], acc[kk][1], acc[kk][2], acc[kk][3]};
                __builtin_nontemporal_store(v, (f32x4*)(out + base) + t);
            }
        }
    }

    // ---- degenerate overflow path (cnt_n > CAPC): rows above hold diag+zeros;
    //      add every incident edge via global atomics (block-uniform branch) ----
    if (cnt_n > CAPC) {
        __syncthreads();
        for (int t = tid; t < 2 * E; t += 256) {
            int e = t >> 1, side = t & 1;
            int node  = side ? eidx[E + e] : eidx[e];
            if (node != n1) continue;
            int other = side ? eidx[e] : eidx[E + e];
            float sx = ecs[e * 3], sy = ecs[e * 3 + 1], sz = ecs[e * 3 + 2];
            for (int kk = 0; kk < kb; ++kk) {
                float dot = kp_sh[kk * 3] * sx + kp_sh[kk * 3 + 1] * sy
                          + kp_sh[kk * 3 + 2] * sz;
                float th = TWO_PI * dot;
                long base = ((long)(k0 + kk) * DIM + a) * (long)rowf;
                if (CPLX) {
                    float sn, co;
                    sincosf(th, &sn, &co);
                    for (int c = 0; c < 13; ++c) {
                        float h = ef[(long)e * 169 + (side ? pm_d[c] : pm_s[c])];
                        atomicAdd(out + base + (other * 13 + c) * 2,     h * co);
                        atomicAdd(out + base + (other * 13 + c) * 2 + 1, side ? h * sn : -h * sn);
                    }
                } else {
                    float co = cosf(th);
                    for (int c = 0; c < 13; ++c) {
                        float h = ef[(long)e * 169 + (side ? pm_d[c] : pm_s[c])];
                        atomicAdd(out + base + other * 13 + c, h * co);
                    }
                }
            }
        }
    }
}

// ====================== fallback path (round-3, verified) ==================

__global__ __launch_bounds__(256) void zero_kernel(float* __restrict__ out, long n) {
    long n4 = n >> 2;
    float4* out4 = (float4*)out;
    long i = (long)blockIdx.x * blockDim.x + threadIdx.x;
    long stride = (long)gridDim.x * blockDim.x;
    const float4 z = {0.f, 0.f, 0.f, 0.f};
    for (long t = i; t < n4; t += stride) out4[t] = z;
    if (i == 0) for (long j = n4 << 2; j < n; ++j) out[j] = 0.f;
}

template <int CPLX>
__global__ __launch_bounds__(256) void diag_kernel(const float* __restrict__ nf,
                                                   float* __restrict__ out,
                                                   int N, int total, long out_lim) {
    int t = blockIdx.x * blockDim.x + threadIdx.x;
    if (t >= total) return;
    int per_k = N * 169;
    int k = t / per_k, rem = t - k * per_k;
    int n = rem / 169, idx = rem - n * 169;
    int r = idx / 13, c = idx - r * 13;
    float v = 0.5f * (nf[n * 107 + nmap(r, c)] + nf[n * 107 + nmap(c, r)]);
    long DIM = (long)N * 13;
    long off = ((long)k * DIM + (long)n * 13 + r) * DIM + (long)n * 13 + c;
    if (CPLX) off *= 2;
    if (off >= 0 && off < out_lim) out[off] = v;
}

template <int CPLX>
__global__ __launch_bounds__(256) void edge_kernel(const float* __restrict__ ef,
                                                   const float* __restrict__ kp,
                                                   const float* __restrict__ ecs,
                                                   const int*   __restrict__ eidx,
                                                   float* __restrict__ out,
                                                   int N, int E, int K, long out_lim) {
    const int e = blockIdx.x;
    __shared__ float hop_sh[169];
    __shared__ float cos_sh[32];
    __shared__ float sin_sh[32];
    const int tid = threadIdx.x;
    const int r = tid / 13, c = tid - r * 13;

    if (tid < 169) hop_sh[tid] = ef[(long)e * 169 + pmap(r, c)];
    if (tid < K && tid < 32) {
        float sx = ecs[e * 3 + 0], sy = ecs[e * 3 + 1], sz = ecs[e * 3 + 2];
        float dot = kp[tid * 3 + 0] * sx + kp[tid * 3 + 1] * sy + kp[tid * 3 + 2] * sz;
        float th = TWO_PI * dot;
        float s, co;
        sincosf(th, &s, &co);
        cos_sh[tid] = co;
        sin_sh[tid] = s;
    }
    __syncthreads();
    if (tid >= 169) return;

    const int src = eidx[e];
    const int dst = eidx[E + e];
    const long DIM = (long)N * 13;
    const long SL  = DIM * DIM;
    const float h  = hop_sh[tid];
    const float ht = hop_sh[c * 13 + r];
    const long base1 = ((long)src * 13 + r) * DIM + (long)dst * 13 + c;
    const long base2 = ((long)dst * 13 + r) * DIM + (long)src * 13 + c;

    for (int k = 0; k < K; ++k) {
        float co = cos_sh[k & 31];
        float si = sin_sh[k & 31];
        if (CPLX) {
            long o1 = ((long)k * SL + base1) * 2;
            long o2 = ((long)k * SL + base2) * 2;
            if (o1 >= 0 && o1 + 1 < out_lim) {
                atomicAdd(out + o1,      h * co);
                atomicAdd(out + o1 + 1, -h * si);
            }
            if (o2 >= 0 && o2 + 1 < out_lim) {
                atomicAdd(out + o2,     ht * co);
                atomicAdd(out + o2 + 1, ht * si);
            }
        } else {
            long o1 = (long)k * SL + base1;
            long o2 = (long)k * SL + base2;
            if (o1 >= 0 && o1 < out_lim) atomicAdd(out + o1, h * co);
            if (o2 >= 0 && o2 < out_lim) atomicAdd(out + o2, ht * co);
        }
    }
}

// ================================ launch ===================================

extern "C" void kernel_launch(void* const* d_in, const int* in_sizes, int n_in,
                              void* d_out, int out_size, void* d_ws, size_t ws_size,
                              hipStream_t stream) {
    const float* ef   = (const float*)d_in[0];   // edge_features   (E, 169)
    const float* nf   = (const float*)d_in[1];   // node_features   (N, 107)
    const float* kp   = (const float*)d_in[2];   // kpoints         (K, 3)
    const float* ecs  = (const float*)d_in[3];   // edge_cell_shift (E, 3)
    const int*   eidx = (const int*)d_in[4];     // edge_index      (2, E)

    const int E = in_sizes[0] / 169;
    const int N = in_sizes[1] / 107;
    const int K = in_sizes[2] / 3;

    float* out = (float*)d_out;
    const long DIM  = (long)N * 13;
    const long SL   = DIM * DIM;
    const long full = (long)K * SL * 2;
    const int  cplx = ((long)out_size >= full) ? 1 : 0;
    const long out_lim = (long)out_size;

    const int  rowf = (int)DIM * (cplx ? 2 : 1);
    // ws: cnt[N] | bkt[N*CAPC]   (ints)
    const long ws_ints = (long)N + (long)N * CAPC;
    const bool fast_ok = (N >= 1) && (N <= 256) && (K >= 1) &&
                         (E >= 1) && (E < 131072) && (rowf % 4 == 0) &&
                         (ws_size >= (size_t)(ws_ints * 4)) &&
                         ((long)out_size == (long)K * SL * (cplx ? 2 : 1));

    if (fast_ok) {
        int* cnt = (int*)d_ws;
        int* bkt = cnt + N;

        (void)hipMemsetAsync(cnt, 0, (size_t)N * sizeof(int), stream);
        bucket_fill<<<(E + 255) / 256, 256, 0, stream>>>(eidx, cnt, bkt, E);

        if (cplx) {
            constexpr int KB = 4;
            int kgroups = (K + KB - 1) / KB;
            hr2hk_main<1, KB><<<kgroups * (int)DIM, 256, 0, stream>>>(
                ef, nf, kp, ecs, eidx, cnt, bkt, out, N, E, K);
        } else {
            constexpr int KB = 8;
            int kgroups = (K + KB - 1) / KB;
            hr2hk_main<0, KB><<<kgroups * (int)DIM, 256, 0, stream>>>(
                ef, nf, kp, ecs, eidx, cnt, bkt, out, N, E, K);
        }
    } else {
        // verified round-3 fallback
        zero_kernel<<<2048, 256, 0, stream>>>(out, out_lim);
        int total_diag = K * N * 169;
        int blocks_diag = (total_diag + 255) / 256;
        if (cplx) {
            diag_kernel<1><<<blocks_diag, 256, 0, stream>>>(nf, out, N, total_diag, out_lim);
            edge_kernel<1><<<E, 256, 0, stream>>>(ef, kp, ecs, eidx, out, N, E, K, out_lim);
        } else {
            diag_kernel<0><<<blocks_diag, 256, 0, stream>>>(nf, out, N, total_diag, out_lim);
            edge_kernel<0><<<E, 256, 0, stream>>>(ef, kp, ecs, eidx, out, N, E, K, out_lim);
        }
    }
}

// Round 14
// 53.934 us; speedup vs baseline: 1.4087x; 1.4087x over previous
//
#include <hip/hip_runtime.h>

// ---------------------------------------------------------------------------
// HR2HK: H[k, N*13, N*13] from edge/node features, Hermitian fold-in.
// ROUND-9 CONFIGURATION (session best, 54.27 µs verified). Reverted here after
// r10 (row-pairing), r11 (edge precompute), r13 (nontemporal stores) each
// regressed — this structure is the measured local optimum.
// Launch sequence:
//  hipMemsetAsync(cnt) : clear per-node counters
//  bucket_fill         : per-node incident-entry buckets via global atomics
//                        (packed (other<<18)|(e<<1)|flag). No CSR, no scan.
//  hr2hk_main (DIM x kgroups blocks): block (a=n1*13+r, kg) stages incident
//    entries ONCE (hop 13-segments, per-(entry,k) phases with ecs read
//    straight from L2, chain index by other-node; 2 barriers), then a
//    BARRIER-FREE stream loop: each thread walks the chain ONCE per
//    column-quad, accumulates ALL KB k-slices in registers (static
//    indexing), and issues KB coalesced float4 stores. Every output byte
//    written exactly once; no global atomics.
// Dual layout keyed off out_size (proven round 3):
//   out_size >= 2*K*DIM^2 : interleaved complex64 ; else real-part-only f32.
// Node-degree overflow -> correct in-block global-atomic path (never taken).
// Guard failure -> verified round-3 3-kernel fallback.
// ---------------------------------------------------------------------------

// orbital structure: l = [0,0,1,1,2], sizes {1,1,3,3,5}, offsets {0,1,2,5,8}
__device__ __forceinline__ void orb_of(int r, int& i, int& ri, int& nv) {
    if (r < 1)      { i = 0; ri = r;     nv = 1; }
    else if (r < 2) { i = 1; ri = r - 1; nv = 1; }
    else if (r < 5) { i = 2; ri = r - 2; nv = 3; }
    else if (r < 8) { i = 3; ri = r - 5; nv = 3; }
    else            { i = 4; ri = r - 8; nv = 5; }
}
__device__ __forceinline__ int offs_of(int i) {
    return i == 0 ? 0 : (i == 1 ? 1 : (i == 2 ? 2 : (i == 3 ? 5 : 8)));
}
__device__ __forceinline__ int rowstart_of(int i) {   // {0,13,25,58,82}
    return i == 0 ? 0 : (i == 1 ? 13 : (i == 2 ? 25 : (i == 3 ? 58 : 82)));
}
__device__ __forceinline__ int pmap(int r, int c) {
    int i, ri, nvi, j, cj, nvj;
    orb_of(r, i, ri, nvi);
    orb_of(c, j, cj, nvj);
    return 13 * offs_of(i) + nvi * offs_of(j) + ri * nvj + cj;
}
__device__ __forceinline__ int nmap(int r, int c) {
    int i, ri, nvi, j, cj, nvj;
    orb_of(r, i, ri, nvi);
    orb_of(c, j, cj, nvj);
    if (i <= j)
        return rowstart_of(i) + nvi * (offs_of(j) - offs_of(i)) + ri * nvj + cj;
    else
        return rowstart_of(j) + nvj * (offs_of(i) - offs_of(j)) + cj * nvi + ri;
}

constexpr float TWO_PI = 6.28318530717958647692f;
constexpr int CAPC = 128;   // per-node incident-entry capacity

// ========================= prep: per-node buckets ==========================
__global__ __launch_bounds__(256) void bucket_fill(const int* __restrict__ eidx,
                                                   int* __restrict__ cnt,
                                                   int* __restrict__ bkt,
                                                   int E) {
    int e = blockIdx.x * 256 + threadIdx.x;
    if (e >= E) return;
    int s = eidx[e], d = eidx[E + e];
    int p = atomicAdd(&cnt[s], 1);
    if (p < CAPC) bkt[s * CAPC + p] = (d << 18) | (e << 1);
    int q = atomicAdd(&cnt[d], 1);
    if (q < CAPC) bkt[d * CAPC + q] = (s << 18) | (e << 1) | 1;
}

// ============================ main row kernel ==============================
// block = (kg, a): computes rows a of k-slices [kg*KB, kg*KB+kb) with the
// chain walked ONCE per column, k accumulated in registers.
template <int CPLX, int KB>
__global__ __launch_bounds__(256) void hr2hk_main(const float* __restrict__ ef,
                                                  const float* __restrict__ nf,
                                                  const float* __restrict__ kp,
                                                  const float* __restrict__ ecs,
                                                  const int*   __restrict__ eidx,
                                                  const int*   __restrict__ cnt,
                                                  const int*   __restrict__ bkt,
                                                  float* __restrict__ out,
                                                  int N, int E, int K) {
    const int DIM  = N * 13;
    const int rowf = CPLX ? DIM * 2 : DIM;   // floats per row (mult of 4, guarded)
    const int row4 = rowf >> 2;
    const int a   = blockIdx.x % DIM;
    const int kg  = blockIdx.x / DIM;
    const int n1  = a / 13, r = a - n1 * 13;
    const int k0  = kg * KB;
    const int kb  = (K - k0 < KB) ? (K - k0) : KB;
    const int tid = threadIdx.x;

    __shared__ float h_sh[CAPC * 13];
    __shared__ float ph_sh[CAPC * KB * (CPLX ? 2 : 1)];
    __shared__ int   lst[CAPC];
    __shared__ int   head[256];
    __shared__ int   nxt[CAPC];
    __shared__ float dseg[13];
    __shared__ int   pm_s[13], pm_d[13];
    __shared__ float kp_sh[KB * 3];

    const int cnt_n = cnt[n1];
    const int cb = (cnt_n > CAPC) ? 0 : cnt_n;   // overflow -> gather path off

    head[tid] = -1;
    if (tid < 13) {
        pm_s[tid] = pmap(r, tid);
        pm_d[tid] = pmap(tid, r);
        dseg[tid] = 0.5f * (nf[n1 * 107 + nmap(r, tid)] + nf[n1 * 107 + nmap(tid, r)]);
    }
    if (tid < kb * 3) kp_sh[tid] = kp[k0 * 3 + tid];
    if (tid < cb) lst[tid] = bkt[n1 * CAPC + tid];
    __syncthreads();

    // chain build + phases (ecs straight from L2) + hop staging, one barrier
    if (tid < cb) {
        int o = (int)((unsigned)lst[tid] >> 18);
        nxt[tid] = atomicExch(&head[o], tid);
    }
    for (int t = tid; t < cb * KB; t += 256) {
        int li = t / KB, kk = t - li * KB;
        if (kk < kb) {
            int entry = lst[li];
            int e = (int)(((unsigned)entry >> 1) & 0x1FFFF);
            float sx = ecs[e * 3], sy = ecs[e * 3 + 1], sz = ecs[e * 3 + 2];
            float dot = kp_sh[kk * 3]     * sx
                      + kp_sh[kk * 3 + 1] * sy
                      + kp_sh[kk * 3 + 2] * sz;
            float th = TWO_PI * dot;
            if (CPLX) {
                float sn, co;
                sincosf(th, &sn, &co);
                ph_sh[(li * KB + kk) * 2]     = co;
                ph_sh[(li * KB + kk) * 2 + 1] = (entry & 1) ? sn : -sn;  // pre-folded
            } else {
                ph_sh[li * KB + kk] = cosf(th);
            }
        }
    }
    for (int t = tid; t < cb * 13; t += 256) {
        int li = t / 13, c = t - li * 13;
        int entry = lst[li];
        int e = (int)(((unsigned)entry >> 1) & 0x1FFFF);
        h_sh[li * 13 + c] = ef[(long)e * 169 + ((entry & 1) ? pm_d[c] : pm_s[c])];
    }
    __syncthreads();

    // ---- barrier-free streaming: chain walked once per col, k in registers --
    for (int t = tid; t < row4; t += 256) {
        float acc[KB][4];                       // static indexing (unrolled)
        if (CPLX) {
#pragma unroll
            for (int j = 0; j < 2; ++j) {       // two complex cols per float4
                int col = 2 * t + j;
                int o = (int)((unsigned)col / 13u);
                int cc = col - o * 13;
                float dre = (o == n1) ? dseg[cc] : 0.f;
#pragma unroll
                for (int kk = 0; kk < KB; ++kk) {
                    acc[kk][2 * j]     = dre;
                    acc[kk][2 * j + 1] = 0.f;
                }
                for (int li = head[o]; li >= 0; li = nxt[li]) {
                    float h = h_sh[li * 13 + cc];
#pragma unroll
                    for (int kk = 0; kk < KB; ++kk) {
                        acc[kk][2 * j]     += h * ph_sh[(li * KB + kk) * 2];
                        acc[kk][2 * j + 1] += h * ph_sh[(li * KB + kk) * 2 + 1];
                    }
                }
            }
        } else {
#pragma unroll
            for (int j = 0; j < 4; ++j) {
                int col = 4 * t + j;
                int o = (int)((unsigned)col / 13u);
                int cc = col - o * 13;
                float d = (o == n1) ? dseg[cc] : 0.f;
#pragma unroll
                for (int kk = 0; kk < KB; ++kk) acc[kk][j] = d;
                for (int li = head[o]; li >= 0; li = nxt[li]) {
                    float h = h_sh[li * 13 + cc];
#pragma unroll
                    for (int kk = 0; kk < KB; ++kk)
                        acc[kk][j] += h * ph_sh[li * KB + kk];
                }
            }
        }
#pragma unroll
        for (int kk = 0; kk < KB; ++kk) {
            if (kk < kb) {
                long base = ((long)(k0 + kk) * DIM + a) * (long)rowf;
                float4 v = {acc[kk][0], acc[kk][1], acc[kk][2], acc[kk][3]};
                ((float4*)(out + base))[t] = v;
            }
        }
    }

    // ---- degenerate overflow path (cnt_n > CAPC): rows above hold diag+zeros;
    //      add every incident edge via global atomics (block-uniform branch) ----
    if (cnt_n > CAPC) {
        __syncthreads();
        for (int t = tid; t < 2 * E; t += 256) {
            int e = t >> 1, side = t & 1;
            int node  = side ? eidx[E + e] : eidx[e];
            if (node != n1) continue;
            int other = side ? eidx[e] : eidx[E + e];
            float sx = ecs[e * 3], sy = ecs[e * 3 + 1], sz = ecs[e * 3 + 2];
            for (int kk = 0; kk < kb; ++kk) {
                float dot = kp_sh[kk * 3] * sx + kp_sh[kk * 3 + 1] * sy
                          + kp_sh[kk * 3 + 2] * sz;
                float th = TWO_PI * dot;
                long base = ((long)(k0 + kk) * DIM + a) * (long)rowf;
                if (CPLX) {
                    float sn, co;
                    sincosf(th, &sn, &co);
                    for (int c = 0; c < 13; ++c) {
                        float h = ef[(long)e * 169 + (side ? pm_d[c] : pm_s[c])];
                        atomicAdd(out + base + (other * 13 + c) * 2,     h * co);
                        atomicAdd(out + base + (other * 13 + c) * 2 + 1, side ? h * sn : -h * sn);
                    }
                } else {
                    float co = cosf(th);
                    for (int c = 0; c < 13; ++c) {
                        float h = ef[(long)e * 169 + (side ? pm_d[c] : pm_s[c])];
                        atomicAdd(out + base + other * 13 + c, h * co);
                    }
                }
            }
        }
    }
}

// ====================== fallback path (round-3, verified) ==================

__global__ __launch_bounds__(256) void zero_kernel(float* __restrict__ out, long n) {
    long n4 = n >> 2;
    float4* out4 = (float4*)out;
    long i = (long)blockIdx.x * blockDim.x + threadIdx.x;
    long stride = (long)gridDim.x * blockDim.x;
    const float4 z = {0.f, 0.f, 0.f, 0.f};
    for (long t = i; t < n4; t += stride) out4[t] = z;
    if (i == 0) for (long j = n4 << 2; j < n; ++j) out[j] = 0.f;
}

template <int CPLX>
__global__ __launch_bounds__(256) void diag_kernel(const float* __restrict__ nf,
                                                   float* __restrict__ out,
                                                   int N, int total, long out_lim) {
    int t = blockIdx.x * blockDim.x + threadIdx.x;
    if (t >= total) return;
    int per_k = N * 169;
    int k = t / per_k, rem = t - k * per_k;
    int n = rem / 169, idx = rem - n * 169;
    int r = idx / 13, c = idx - r * 13;
    float v = 0.5f * (nf[n * 107 + nmap(r, c)] + nf[n * 107 + nmap(c, r)]);
    long DIM = (long)N * 13;
    long off = ((long)k * DIM + (long)n * 13 + r) * DIM + (long)n * 13 + c;
    if (CPLX) off *= 2;
    if (off >= 0 && off < out_lim) out[off] = v;
}

template <int CPLX>
__global__ __launch_bounds__(256) void edge_kernel(const float* __restrict__ ef,
                                                   const float* __restrict__ kp,
                                                   const float* __restrict__ ecs,
                                                   const int*   __restrict__ eidx,
                                                   float* __restrict__ out,
                                                   int N, int E, int K, long out_lim) {
    const int e = blockIdx.x;
    __shared__ float hop_sh[169];
    __shared__ float cos_sh[32];
    __shared__ float sin_sh[32];
    const int tid = threadIdx.x;
    const int r = tid / 13, c = tid - r * 13;

    if (tid < 169) hop_sh[tid] = ef[(long)e * 169 + pmap(r, c)];
    if (tid < K && tid < 32) {
        float sx = ecs[e * 3 + 0], sy = ecs[e * 3 + 1], sz = ecs[e * 3 + 2];
        float dot = kp[tid * 3 + 0] * sx + kp[tid * 3 + 1] * sy + kp[tid * 3 + 2] * sz;
        float th = TWO_PI * dot;
        float s, co;
        sincosf(th, &s, &co);
        cos_sh[tid] = co;
        sin_sh[tid] = s;
    }
    __syncthreads();
    if (tid >= 169) return;

    const int src = eidx[e];
    const int dst = eidx[E + e];
    const long DIM = (long)N * 13;
    const long SL  = DIM * DIM;
    const float h  = hop_sh[tid];
    const float ht = hop_sh[c * 13 + r];
    const long base1 = ((long)src * 13 + r) * DIM + (long)dst * 13 + c;
    const long base2 = ((long)dst * 13 + r) * DIM + (long)src * 13 + c;

    for (int k = 0; k < K; ++k) {
        float co = cos_sh[k & 31];
        float si = sin_sh[k & 31];
        if (CPLX) {
            long o1 = ((long)k * SL + base1) * 2;
            long o2 = ((long)k * SL + base2) * 2;
            if (o1 >= 0 && o1 + 1 < out_lim) {
                atomicAdd(out + o1,      h * co);
                atomicAdd(out + o1 + 1, -h * si);
            }
            if (o2 >= 0 && o2 + 1 < out_lim) {
                atomicAdd(out + o2,     ht * co);
                atomicAdd(out + o2 + 1, ht * si);
            }
        } else {
            long o1 = (long)k * SL + base1;
            long o2 = (long)k * SL + base2;
            if (o1 >= 0 && o1 < out_lim) atomicAdd(out + o1, h * co);
            if (o2 >= 0 && o2 < out_lim) atomicAdd(out + o2, ht * co);
        }
    }
}

// ================================ launch ===================================

extern "C" void kernel_launch(void* const* d_in, const int* in_sizes, int n_in,
                              void* d_out, int out_size, void* d_ws, size_t ws_size,
                              hipStream_t stream) {
    const float* ef   = (const float*)d_in[0];   // edge_features   (E, 169)
    const float* nf   = (const float*)d_in[1];   // node_features   (N, 107)
    const float* kp   = (const float*)d_in[2];   // kpoints         (K, 3)
    const float* ecs  = (const float*)d_in[3];   // edge_cell_shift (E, 3)
    const int*   eidx = (const int*)d_in[4];     // edge_index      (2, E)

    const int E = in_sizes[0] / 169;
    const int N = in_sizes[1] / 107;
    const int K = in_sizes[2] / 3;

    float* out = (float*)d_out;
    const long DIM  = (long)N * 13;
    const long SL   = DIM * DIM;
    const long full = (long)K * SL * 2;
    const int  cplx = ((long)out_size >= full) ? 1 : 0;
    const long out_lim = (long)out_size;

    const int  rowf = (int)DIM * (cplx ? 2 : 1);
    // ws: cnt[N] | bkt[N*CAPC]   (ints)
    const long ws_ints = (long)N + (long)N * CAPC;
    const bool fast_ok = (N >= 1) && (N <= 256) && (K >= 1) &&
                         (E >= 1) && (E < 131072) && (rowf % 4 == 0) &&
                         (ws_size >= (size_t)(ws_ints * 4)) &&
                         ((long)out_size == (long)K * SL * (cplx ? 2 : 1));

    if (fast_ok) {
        int* cnt = (int*)d_ws;
        int* bkt = cnt + N;

        (void)hipMemsetAsync(cnt, 0, (size_t)N * sizeof(int), stream);
        bucket_fill<<<(E + 255) / 256, 256, 0, stream>>>(eidx, cnt, bkt, E);

        if (cplx) {
            constexpr int KB = 4;
            int kgroups = (K + KB - 1) / KB;
            hr2hk_main<1, KB><<<kgroups * (int)DIM, 256, 0, stream>>>(
                ef, nf, kp, ecs, eidx, cnt, bkt, out, N, E, K);
        } else {
            constexpr int KB = 8;
            int kgroups = (K + KB - 1) / KB;
            hr2hk_main<0, KB><<<kgroups * (int)DIM, 256, 0, stream>>>(
                ef, nf, kp, ecs, eidx, cnt, bkt, out, N, E, K);
        }
    } else {
        // verified round-3 fallback
        zero_kernel<<<2048, 256, 0, stream>>>(out, out_lim);
        int total_diag = K * N * 169;
        int blocks_diag = (total_diag + 255) / 256;
        if (cplx) {
            diag_kernel<1><<<blocks_diag, 256, 0, stream>>>(nf, out, N, total_diag, out_lim);
            edge_kernel<1><<<E, 256, 0, stream>>>(ef, kp, ecs, eidx, out, N, E, K, out_lim);
        } else {
            diag_kernel<0><<<blocks_diag, 256, 0, stream>>>(nf, out, N, total_diag, out_lim);
            edge_kernel<0><<<E, 256, 0, stream>>>(ef, kp, ecs, eidx, out, N, E, K, out_lim);
        }
    }
}